// Round 6
// baseline (70.413 us; speedup 1.0000x reference)
//
#include <hip/hip_runtime.h>

// K[b,i,j] = exp(-|xi-xj|^2/2), points [4,4096,64] fp32, out [4,4096,4096] fp32.
// Single bf16 MFMA Gram GEMM, fp32->bf16 conversion fused into staging.
// Norms computed from the SAME bf16 values so inner - na - nb ==
// -0.5*|hi(x)-hi(y)|^2 algebraically; diagonal forced to 1.
// Tile 64x256: each block writes 1 KB contiguous per row; 16 consecutive
// blocks (bx-fastest) fill a 1 MB contiguous row-stripe (write streaming).
// NOTE: nontemporal stores regressed (82 vs 60 us) - keep cached stores.

#define NPTS 4096
#define DDIM 64
#define BM 64
#define BN 256
#define GX (NPTS / BN)   // 16
#define GY (NPTS / BM)   // 64

typedef __attribute__((ext_vector_type(8))) short bf16x8;
typedef __attribute__((ext_vector_type(4))) float f32x4;

__device__ __forceinline__ ushort bf16_rne(float x) {
    union { float f; unsigned u; } v; v.f = x;
    unsigned r = v.u + 0x7fffu + ((v.u >> 16) & 1u);
    return (ushort)(r >> 16);
}
__device__ __forceinline__ float bf16_f(ushort b) {
    union { float f; unsigned u; } v; v.u = ((unsigned)b) << 16;
    return v.f;
}

__global__ __launch_bounds__(256, 3)
void KernelDistance_74972949119307_kernel(const float* __restrict__ pts,
                                          float* __restrict__ out) {
    __shared__ ushort Ah[BM * DDIM];   // 8 KB, swizzled chunks
    __shared__ ushort Bh[BN * DDIM];   // 32 KB
    __shared__ float na_s[BM];
    __shared__ float nb_s[BN];

    const int bx = blockIdx.x, by = blockIdx.y, bz = blockIdx.z;
    const int tid = threadIdx.x;
    const int cl = tid & 7;            // chunk lane within row (8 chunks/row)

    // ---- Stage + convert fp32->bf16 + per-row half-norms (from bf16) ----
#pragma unroll
    for (int tile = 0; tile < 2; ++tile) {
        const int rows = tile ? BN : BM;
        const size_t rb = ((size_t)bz * NPTS + (size_t)(tile ? bx * BN : by * BM)) * DDIM;
        ushort* L = tile ? Bh : Ah;
        float* ns = tile ? nb_s : na_s;
        const int iters = rows * 8 / 256;
#pragma unroll
        for (int k = 0; k < iters; ++k) {
            const int f = k * 256 + tid;       // 16B-chunk index
            const int row = f >> 3;
            const float4* g4 = (const float4*)(pts + rb) + (size_t)f * 2;
            const float4 v0 = g4[0], v1 = g4[1];
            const float fv[8] = {v0.x, v0.y, v0.z, v0.w, v1.x, v1.y, v1.z, v1.w};
            union { ushort us[8]; bf16x8 v; } H;
            float s = 0.f;
#pragma unroll
            for (int j = 0; j < 8; ++j) {
                H.us[j] = bf16_rne(fv[j]);
                const float x = bf16_f(H.us[j]);
                s += x * x;
            }
            s += __shfl_xor(s, 1);
            s += __shfl_xor(s, 2);
            s += __shfl_xor(s, 4);
            *(bf16x8*)&L[row * DDIM + ((f & 7) ^ (row & 7)) * 8] = H.v;
            if (cl == 0) ns[row] = 0.5f * s;
        }
    }
    __syncthreads();

    // ---- 4 waves 2x2: each wave 32x128 = 2x8 tiles of 16x16, K=64 ----
    const int lane = tid & 63;
    const int wid = tid >> 6;
    const int wm = (wid >> 1) * 32;
    const int wn = (wid & 1) * 128;
    const int ml = lane & 15;
    const int g = lane >> 4;

    f32x4 acc[2][8];
#pragma unroll
    for (int mt = 0; mt < 2; ++mt)
#pragma unroll
        for (int nt = 0; nt < 8; ++nt)
            acc[mt][nt] = (f32x4){0.f, 0.f, 0.f, 0.f};

#pragma unroll
    for (int s = 0; s < 2; ++s) {
        bf16x8 a[2], b[8];
#pragma unroll
        for (int mt = 0; mt < 2; ++mt) {
            const int row = wm + mt * 16 + ml;
            const int c = (4 * s + g) ^ (row & 7);
            a[mt] = *(const bf16x8*)&Ah[row * DDIM + c * 8];
        }
#pragma unroll
        for (int nt = 0; nt < 8; ++nt) {
            const int row = wn + nt * 16 + ml;
            const int c = (4 * s + g) ^ (row & 7);
            b[nt] = *(const bf16x8*)&Bh[row * DDIM + c * 8];
        }
        // Swapped operands: thread owns (i = wm+mt*16+ml, j = wn+nt*16+g*4+reg)
#pragma unroll
        for (int mt = 0; mt < 2; ++mt)
#pragma unroll
            for (int nt = 0; nt < 8; ++nt)
                acc[mt][nt] = __builtin_amdgcn_mfma_f32_16x16x32_bf16(b[nt], a[mt], acc[mt][nt], 0, 0, 0);
    }

    // ---- Epilogue: K = exp(min(inner - na - nb, 0)); K_ii = 1 ----
    f32x4 nbq[8];
#pragma unroll
    for (int nt = 0; nt < 8; ++nt)
        nbq[nt] = *(const f32x4*)&nb_s[wn + nt * 16 + g * 4];

    float* outB = out + ((size_t)bz * NPTS + (size_t)by * BM) * NPTS + (size_t)bx * BN;
    const int dof = by * BM - bx * BN;        // global diag: local j == local i + dof
    const bool diagblk = ((by >> 2) == bx);

#pragma unroll
    for (int mt = 0; mt < 2; ++mt) {
        const int i = wm + mt * 16 + ml;
        const float nav = na_s[i];
        float* orow = outB + (size_t)i * NPTS;
#pragma unroll
        for (int nt = 0; nt < 8; ++nt) {
            const int j0 = wn + nt * 16 + g * 4;
            f32x4 o;
#pragma unroll
            for (int r = 0; r < 4; ++r) {
                const float v = acc[mt][nt][r] - (nav + nbq[nt][r]);
                o[r] = __expf(fminf(v, 0.f));
            }
            if (diagblk) {
                const int d = i + dof - j0;
                o[0] = (d == 0) ? 1.0f : o[0];
                o[1] = (d == 1) ? 1.0f : o[1];
                o[2] = (d == 2) ? 1.0f : o[2];
                o[3] = (d == 3) ? 1.0f : o[3];
            }
            *(f32x4*)&orow[j0] = o;
        }
    }
}

extern "C" void kernel_launch(void* const* d_in, const int* in_sizes, int n_in,
                              void* d_out, int out_size, void* d_ws, size_t ws_size,
                              hipStream_t stream) {
    const float* pts = (const float*)d_in[0];
    float* out = (float*)d_out;
    dim3 grid(GX, GY, 4);
    KernelDistance_74972949119307_kernel<<<grid, 256, 0, stream>>>(pts, out);
}